// Round 9
// baseline (451.839 us; speedup 1.0000x reference)
//
#include <hip/hip_runtime.h>

// Problem constants
#define BQ 8
#define CQ 16
#define LQ 2048
#define NQ 2048
#define NPS 128      // nperseg
#define STEPQ 64     // step (50% overlap)
#define SQ 31        // segments per series
#define FQ 65        // rfft bins
#define KQ 32        // nref
#define EPSQ 1e-12f

// ---- workspace layout (bytes) ----
#define XQ_OFF     0ull
#define XTAIL_OFF  2031616ull
#define PXX_OFF    2063360ull                    // float [B][C][F] = 8320 floats
#define SCORES_OFF 2096640ull                    // float [B][C][N] = 262144 floats
#define TOPK_OFF   3145216ull                    // int [B][C][K] = 8192 ints
#define WTAB_OFF   3177984ull                    // float[128] Hann window
#define WROT_OFF   3178496ull                    // float2[8][16] H-twiddle table (ends 3179520)

// ---- shared memory layout (float offsets) ----
// Y rows: float2 [31][YLD], bins 0..64 at natural columns, YLD=66 keeps the
// score-loop reads 16B-aligned (2x ds_read_b128 per s-iter — the hot path).
#define YLD 66
#define OFF_Y     0                              // float2[31*66] = 4092 floats
#define OFF_PYY   4092                           // 65
#define OFF_RED   4157                           // 256
#define SMEM_FLOATS 4413                         // 17652 B -> 8 blocks/CU (wave-capped)

// compile-time {cos(2pi j/16), -sin(2pi j/16)} pairs (j folded constant after unroll)
#define C16R(j) ((j)==0?1.0f:(j)==1?0.92387953251128675613f:(j)==2?0.70710678118654752440f:\
    (j)==3?0.38268343236508977173f:(j)==4?0.0f:(j)==5?-0.38268343236508977173f:\
    (j)==6?-0.70710678118654752440f:(j)==7?-0.92387953251128675613f:(j)==8?-1.0f:\
    (j)==9?-0.92387953251128675613f:(j)==10?-0.70710678118654752440f:(j)==11?-0.38268343236508977173f:\
    (j)==12?0.0f:(j)==13?0.38268343236508977173f:(j)==14?0.70710678118654752440f:0.92387953251128675613f)
#define C16I(j) (-((j)==0?0.0f:(j)==1?0.38268343236508977173f:(j)==2?0.70710678118654752440f:\
    (j)==3?0.92387953251128675613f:(j)==4?1.0f:(j)==5?0.92387953251128675613f:\
    (j)==6?0.70710678118654752440f:(j)==7?0.38268343236508977173f:(j)==8?0.0f:\
    (j)==9?-0.38268343236508977173f:(j)==10?-0.70710678118654752440f:(j)==11?-0.92387953251128675613f:\
    (j)==12?-1.0f:(j)==13?-0.92387953251128675613f:(j)==14?-0.70710678118654752440f:-0.38268343236508977173f))

// stage-A butterfly twiddles W8^{t1-4} for t1>=4, identity for t1<4
__device__ __constant__ const float WA_R[8] = {1.f, 1.f, 1.f, 1.f,
    1.f, 0.70710678118654752440f, 0.f, -0.70710678118654752440f};
__device__ __constant__ const float WA_I[8] = {0.f, 0.f, 0.f, 0.f,
    0.f, -0.70710678118654752440f, -1.f, -0.70710678118654752440f};
__device__ __constant__ const int BR3_[8] = {0, 4, 2, 6, 1, 5, 3, 7};

#define TWOPI_128 0.049087385212340519350978802863742f   // 2*pi/128

// ---- DPP lane-xor (all on the VALU pipe — no LDS-pipe cross-lane ops) ----
__device__ __forceinline__ float dppx1(float v) {   // lane ^ 1: quad_perm [1,0,3,2] = 0xB1
    return __int_as_float(__builtin_amdgcn_update_dpp(0, __float_as_int(v), 0xB1, 0xF, 0xF, true));
}
__device__ __forceinline__ float dppx2(float v) {   // lane ^ 2: quad_perm [2,3,0,1] = 0x4E
    return __int_as_float(__builtin_amdgcn_update_dpp(0, __float_as_int(v), 0x4E, 0xF, 0xF, true));
}
__device__ __forceinline__ float dppx8(float v) {   // lane ^ 8: row_ror:8 = 0x128 (16-row)
    return __int_as_float(__builtin_amdgcn_update_dpp(0, __float_as_int(v), 0x128, 0xF, 0xF, true));
}

// ---- VOP3P packed-fp32 helpers (proven) ----
// complex X*conj(Y) accumulate, acc={pr,pi}, x={xr,xi}, y={yr,yi}:
__device__ __forceinline__ float2 pk_cma1(float2 x, float2 y, float2 acc) {
    float2 d;
    asm("v_pk_fma_f32 %0, %1, %2, %3 op_sel:[0,0,0] op_sel_hi:[1,0,1]"
        : "=v"(d) : "v"(x), "v"(y), "v"(acc));
    return d;
}
__device__ __forceinline__ float2 pk_cma2(float2 x, float2 y, float2 acc) {
    float2 d;
    asm("v_pk_fma_f32 %0, %1, %2, %3 op_sel:[1,1,0] op_sel_hi:[0,1,1] neg_hi:[1,0,0]"
        : "=v"(d) : "v"(x), "v"(y), "v"(acc));
    return d;
}
// stage-1 DFT: g += x_lo * {cos,-sin}  (a broadcasts lo/hi half; b = SGPR-pair constant)
__device__ __forceinline__ float2 pk_dft_lo(float2 xp, float2 w, float2 g) {
    float2 d;
    asm("v_pk_fma_f32 %0, %1, %2, %3 op_sel:[0,0,0] op_sel_hi:[0,1,1]"
        : "=v"(d) : "v"(xp), "s"(w), "v"(g));
    return d;
}
__device__ __forceinline__ float2 pk_dft_hi(float2 xp, float2 w, float2 g) {
    float2 d;
    asm("v_pk_fma_f32 %0, %1, %2, %3 op_sel:[1,0,0] op_sel_hi:[1,1,1]"
        : "=v"(d) : "v"(xp), "s"(w), "v"(g));
    return d;
}

// Welch spectra of one length-2048 row into smem Y (float2 [31][YLD], cols 0..64).
// Scalar butterfly arithmetic: bitwise-identical to the proven kernel.
// LANE REMAP (r8, proven): t1 bit2 on lane bit3 -> all cross-lane is DPP.
// TWIDDLE TABLE (r9): TAB path loads w(t1,mp) from a 1KB L1-resident table
// generated by the IDENTICAL rotation chain in k_xspec block 0 — removes the
// serial 4-op/iter rotation dependency and ~64 VALU instrs per thread.
// Writes pair-combined into ds_write_b128 (odd mp), single b64 for bin 64.
template<bool TAB>
__device__ __forceinline__ void welch_spectra(const float* __restrict__ grow,
                                              const float* __restrict__ wtab,
                                              const float2* __restrict__ wrot,
                                              float* smem) {
    const int tid = threadIdx.x;
    float2* s_y = (float2*)(smem + OFF_Y);

    const int lane = tid & 63;
    const int t1 = (lane & 3) | ((lane >> 1) & 4);                 // t1 bit2 <- lane bit3
    const int s  = ((tid >> 6) << 3) | ((lane >> 3) & 6) | ((lane >> 2) & 1);
    const bool act = s < SQ;

    float x[16];
    float sum = 0.f;
    if (act) {
        const float* rp = grow + s * STEPQ + t1;
#pragma unroll
        for (int t2 = 0; t2 < 16; ++t2) x[t2] = rp[8 * t2];
#pragma unroll
        for (int t2 = 0; t2 < 16; ++t2) sum += x[t2];
    }
    // segment mean across the 8 t1-lanes (partners: lane^1, lane^2, lane^8 — same s)
    sum += dppx1(sum);
    sum += dppx2(sum);
    sum += dppx8(sum);
    const float mean = sum * (1.0f / 128.0f);

    float2 G[9];
    if (act) {
        float2 xp[8];
#pragma unroll
        for (int t2 = 0; t2 < 16; ++t2) {
            float wv;
            if (TAB) {
                wv = wtab[t1 + 8 * t2];                       // L1-resident, bitwise == inline cos
            } else {
                const float a = (float)(t1 + 8 * t2) * TWOPI_128;
                wv = 0.5f - 0.5f * __cosf(a);
            }
            x[t2] = (x[t2] - mean) * wv;
        }
#pragma unroll
        for (int j = 0; j < 8; ++j) xp[j] = make_float2(x[2 * j], x[2 * j + 1]);
#pragma unroll
        for (int m = 0; m < 9; ++m) {
            float2 g = make_float2(0.f, 0.f);
#pragma unroll
            for (int j = 0; j < 8; ++j) {
                {
                    const int i0 = (m * (2 * j)) & 15;
                    g = pk_dft_lo(xp[j], make_float2(C16R(i0), C16I(i0)), g);
                }
                {
                    const int i1 = (m * (2 * j + 1)) & 15;
                    g = pk_dft_hi(xp[j], make_float2(C16R(i1), C16I(i1)), g);
                }
            }
            G[m] = g;
        }
    }

    // per-lane butterfly constants
    const float s1 = (t1 & 4) ? -1.f : 1.f;
    const float s2 = (t1 & 2) ? -1.f : 1.f;
    const float s3 = (t1 & 1) ? -1.f : 1.f;
    const float war = WA_R[t1], wai = WA_I[t1];
    const bool q3 = (t1 & 3) == 3;
    const int kbase = 16 * BR3_[t1];          // lane t1 owns bins kbase..kbase+15

    // H-twiddle w(m') = e^{-2pi i t1 m'/128}: inline chain (non-TAB) or table (TAB)
    float cr = 0.f, ci = 0.f, wr = 1.f, wi = 0.f;
    if (!TAB) {
        __sincosf((float)t1 * TWOPI_128, &ci, &cr);   // ci=sin, cr=cos
        ci = -ci;
    }

    if (act) {
        float2* yrow = s_y + s * YLD + kbase;
        const float2* wp = wrot + (t1 << 4);
        float2 vprev = make_float2(0.f, 0.f);
#pragma unroll
        for (int mp = 0; mp < 16; ++mp) {
            const int mm = (mp <= 8) ? mp : 16 - mp;
            const float sg = (mp <= 8) ? 1.f : -1.f;   // conj(G) for m'>8 (real input)
            const float gr = G[mm].x, gi = sg * G[mm].y;
            if (TAB) {
                const float2 w2 = wp[mp];              // independent per-mp (no chain)
                wr = w2.x; wi = w2.y;
            }
            float hr = wr * gr - wi * gi;
            float hi = wr * gi + wi * gr;
            // stage A: xor t1-bit2 (= lane^8, DPP row_ror:8), twiddle W8^{t1-4} on upper lanes
            float orr = dppx8(hr), oi = dppx8(hi);
            float vr = fmaf(s1, hr, orr), vi = fmaf(s1, hi, oi);
            hr = vr * war - vi * wai;
            hi = vr * wai + vi * war;
            // stage B: xor 2 (DPP), twiddle -i on q==3 lanes
            orr = dppx2(hr); oi = dppx2(hi);
            vr = fmaf(s2, hr, orr); vi = fmaf(s2, hi, oi);
            hr = q3 ? vi : vr;
            hi = q3 ? -vr : vi;
            // stage C: xor 1 (DPP)
            orr = dppx1(hr); oi = dppx1(hi);
            vr = fmaf(s3, hr, orr); vi = fmaf(s3, hi, oi);
            if (mp & 1) {
                if (kbase + mp <= 64) {            // both bins of pair valid (br3<=3)
                    float4 w4 = make_float4(vprev.x, vprev.y, vr, vi);
                    *(float4*)(yrow + (mp - 1)) = w4;          // ds_write_b128, 16B-aligned
                } else if (kbase + mp == 65) {     // br3==4, mp==1: only bin 64 valid
                    yrow[0] = vprev;                           // single b64 (vprev = bin 64)
                }
            } else {
                vprev = make_float2(vr, vi);
            }
            if (!TAB) {                                        // rotate twiddle (chain)
                const float nwr = wr * cr - wi * ci;
                wi = wr * ci + wi * cr;
                wr = nwr;
            }
        }
    }
    __syncthreads();
}

// Target spectra: one block per (b,c). Writes xquad/xtail and Pxx [B][C][F].
// Block 0 also materializes the Hann window + H-twiddle tables for k_score.
// (k_xspec's own welch keeps the inline chain — its blocks race the table write.)
__global__ __launch_bounds__(256) void k_xspec(const float* __restrict__ tgt,
                                               float2* __restrict__ xquad,
                                               float2* __restrict__ xtail,
                                               float* __restrict__ pxx,
                                               float* __restrict__ wtab,
                                               float2* __restrict__ wrot) {
    __shared__ float smem[SMEM_FLOATS];
    const int blk = blockIdx.x;            // b*16 + c
    const int b = blk >> 4, c = blk & 15;
    const int tid = threadIdx.x;
    if (blk == 0) {
        if (tid < NPS)
            wtab[tid] = 0.5f - 0.5f * __cosf((float)tid * TWOPI_128);
        if (tid < 8) {                     // identical chain as welch<false> -> same bits
            float cr, ci;
            __sincosf((float)tid * TWOPI_128, &ci, &cr);
            ci = -ci;
            float wr = 1.f, wi = 0.f;
            for (int mp = 0; mp < 16; ++mp) {
                wrot[(tid << 4) | mp] = make_float2(wr, wi);
                const float nwr = wr * cr - wi * ci;
                wi = wr * ci + wi * cr;
                wr = nwr;
            }
        }
    }
    welch_spectra<false>(tgt + (size_t)blk * LQ, nullptr, nullptr, smem);
    const float2* s_y = (const float2*)(smem + OFF_Y);
    for (int i = tid; i < SQ * FQ; i += 256) {
        const int s2 = i / 65, k = i - 65 * s2;
        const float2 v = s_y[s2 * YLD + k];
        if (k < 64) {
            const int q = k >> 2, j = k & 3;
            xquad[((((size_t)b * 16 + q) * SQ + s2) * CQ + c) * 4 + j] = v;
        } else {
            xtail[((size_t)b * SQ + s2) * CQ + c] = v;
        }
    }
    if (tid < FQ) {
        float a = 0.f;
        for (int s = 0; s < SQ; ++s) {
            const float2 y = s_y[s * YLD + tid];
            a += y.x * y.x + y.y * y.y;
        }
        pxx[(size_t)blk * FQ + tid] = a * (1.0f / (float)SQ);
    }
}

// exact pk sequence of the proven kernel, as a macro so the pipeline can reuse it
#define SCORE_COMPUTE(XA, XB, YA, YB)                                            \
    do {                                                                         \
        const float2 x0 = make_float2((XA).x, (XA).y), x1 = make_float2((XA).z, (XA).w); \
        const float2 x2 = make_float2((XB).x, (XB).y), x3 = make_float2((XB).z, (XB).w); \
        const float2 y0 = make_float2((YA).x, (YA).y), y1 = make_float2((YA).z, (YA).w); \
        const float2 y2 = make_float2((YB).x, (YB).y), y3 = make_float2((YB).z, (YB).w); \
        a0 = pk_cma1(x0, y0, a0);  a0 = pk_cma2(x0, y0, a0);                     \
        a1 = pk_cma1(x1, y1, a1);  a1 = pk_cma2(x1, y1, a1);                     \
        a2 = pk_cma1(x2, y2, a2);  a2 = pk_cma2(x2, y2, a2);                     \
        a3 = pk_cma1(x3, y3, a3);  a3 = pk_cma2(x3, y3, a3);                     \
    } while (0)

// Score: one block per (b,n). Y spectra, Pyy, coherence vs 16 channels (packed fp32).
// Score loop is software-pipelined (depth 1): loads for s+1 issue before compute
// of s. (Depth-2 and unroll variants collapsed in r5-r7 — depth-1 @ VGPR 40 is
// the stable optimum of this axis.)
__global__ __launch_bounds__(256) void k_score(const float* __restrict__ db,
                                               const float2* __restrict__ xquad,
                                               const float2* __restrict__ xtail,
                                               const float* __restrict__ pxx,
                                               const float* __restrict__ wtab,
                                               const float2* __restrict__ wrot,
                                               float* __restrict__ scores) {
    __shared__ float smem[SMEM_FLOATS];
    const int blk = blockIdx.x;            // b*2048 + n
    const int b = blk >> 11, n = blk & 2047;
    welch_spectra<true>(db + (size_t)blk * LQ, wtab, wrot, smem);
    float* s_pyy = smem + OFF_PYY;
    float* s_red = smem + OFF_RED;
    const int tid = threadIdx.x;

    if (tid < FQ) {
        float a = 0.f;
        for (int s = 0; s < SQ; ++s) {
            const float2 y = ((const float2*)(smem + OFF_Y))[s * YLD + tid];
            a += y.x * y.x + y.y * y.y;
        }
        s_pyy[tid] = a * (1.0f / (float)SQ);
    }
    __syncthreads();

    const int c = tid & 15, g = tid >> 4;
    const int f0 = 4 * g;
    // x quad pointer for (b, q=g, c): 2 float4 per (s,c); stride per s = 32 float4
    const float4* xp = (const float4*)xquad + (((size_t)(b * 16 + g) * SQ) * CQ + c) * 2;
    const float*  px = pxx + ((size_t)b * CQ + c) * FQ;
    const float*  ybase = smem + OFF_Y;
#define YADDR(S) ((const float4*)(ybase + (size_t)((S) * YLD + f0) * 2))

    float2 a0 = make_float2(0.f, 0.f), a1 = a0, a2 = a0, a3 = a0;   // {pr,pi}

    // prologue: s = 0 in flight
    float4 xa = xp[0], xb4 = xp[1];
    xp += 32;
    float4 ya = YADDR(0)[0], yb = YADDR(0)[1];

#pragma unroll 2
    for (int s = 0; s < SQ - 1; ++s) {      // s = 0..29; prefetch s+1 before compute
        const float4 xa_n = xp[0], xb_n = xp[1];
        xp += 32;
        const float4 ya_n = YADDR(s + 1)[0], yb_n = YADDR(s + 1)[1];
        SCORE_COMPUTE(xa, xb4, ya, yb);
        xa = xa_n; xb4 = xb_n; ya = ya_n; yb = yb_n;
    }
    SCORE_COMPUTE(xa, xb4, ya, yb);         // s = 30
#undef YADDR

    const float invS2 = 1.0f / ((float)SQ * (float)SQ);
    float acc = 0.f;
    acc += ((a0.x * a0.x + a0.y * a0.y) * invS2) / (px[f0 + 0] * s_pyy[f0 + 0] + EPSQ);
    acc += ((a1.x * a1.x + a1.y * a1.y) * invS2) / (px[f0 + 1] * s_pyy[f0 + 1] + EPSQ);
    acc += ((a2.x * a2.x + a2.y * a2.y) * invS2) / (px[f0 + 2] * s_pyy[f0 + 2] + EPSQ);
    acc += ((a3.x * a3.x + a3.y * a3.y) * invS2) / (px[f0 + 3] * s_pyy[f0 + 3] + EPSQ);

    if (g == 0) {                            // bin 64 tail, 16 threads
        float2 a4 = make_float2(0.f, 0.f);
        const float2* xt = xtail + (size_t)b * SQ * CQ + c;
        for (int s = 0; s < SQ; ++s) {
            const float2 y4 = ((const float2*)(smem + OFF_Y))[s * YLD + 64];
            const float2 x4 = xt[s * CQ];
            a4 = pk_cma1(x4, y4, a4);  a4 = pk_cma2(x4, y4, a4);
        }
        acc += ((a4.x * a4.x + a4.y * a4.y) * invS2) / (px[64] * s_pyy[64] + EPSQ);
    }

    s_red[tid] = acc;                       // tid = g*16 + c
    __syncthreads();
    if (tid < 16) {
        float a = 0.f;
#pragma unroll
        for (int gg = 0; gg < 16; ++gg) a += s_red[gg * 16 + tid];
        scores[((size_t)b * CQ + tid) * NQ + n] = a * (1.0f / (float)FQ);
    }
}

// Top-32 per (b,c) row, jax.lax.top_k semantics (desc, ties->lowest idx).
// Scores kept register-resident (8/thread); zap via static-index compare.
__global__ __launch_bounds__(256) void k_topk(const float* __restrict__ scores,
                                              int* __restrict__ topk) {
    __shared__ float rv[4];
    __shared__ int   ri[4];
    __shared__ int   sbj;
    const int blk = blockIdx.x, tid = threadIdx.x;
    const float* row = scores + (size_t)blk * NQ;
    float v[8];
#pragma unroll
    for (int j = 0; j < 8; ++j) v[j] = row[tid + 256 * j];
    for (int k = 0; k < KQ; ++k) {
        float best = -3.402823466e38f;
        int bi = 0x7fffffff;
#pragma unroll
        for (int j = 0; j < 8; ++j) {
            if (v[j] > best) { best = v[j]; bi = tid + 256 * j; }  // ascending idx: strict > keeps smallest
        }
#pragma unroll
        for (int off = 1; off < 64; off <<= 1) {
            const float ov = __shfl_xor(best, off, 64);
            const int   oi = __shfl_xor(bi, off, 64);
            if (ov > best || (ov == best && oi < bi)) { best = ov; bi = oi; }
        }
        if ((tid & 63) == 0) { rv[tid >> 6] = best; ri[tid >> 6] = bi; }
        __syncthreads();
        if (tid == 0) {
            float bv = rv[0]; int bj = ri[0];
#pragma unroll
            for (int w2 = 1; w2 < 4; ++w2) {
                if (rv[w2] > bv || (rv[w2] == bv && ri[w2] < bj)) { bv = rv[w2]; bj = ri[w2]; }
            }
            topk[blk * KQ + k] = bj;
            sbj = bj;
        }
        __syncthreads();
        const int bj = sbj;
#pragma unroll
        for (int j = 0; j < 8; ++j)
            if (bj == tid + 256 * j) v[j] = -3.402823466e38f;
    }
}

// Gather: one block per output row (b, c*32+k) -> copy DB row (2048 floats) via float4.
__global__ __launch_bounds__(256) void k_gather(const float* __restrict__ db,
                                                const int* __restrict__ topk,
                                                float* __restrict__ out) {
    const int row = blockIdx.x;               // b*512 + c*32 + k
    const int b = row >> 9;
    const int idx = topk[row];
    const float4* src = (const float4*)(db + ((size_t)(b * NQ + idx)) * LQ);
    float4* dst = (float4*)(out + (size_t)row * LQ);
    const int tid = threadIdx.x;
    dst[tid] = src[tid];
    dst[tid + 256] = src[tid + 256];
}

extern "C" void kernel_launch(void* const* d_in, const int* in_sizes, int n_in,
                              void* d_out, int out_size, void* d_ws, size_t ws_size,
                              hipStream_t stream) {
    const float* tgt = (const float*)d_in[0];   // [8,16,2048]
    const float* db  = (const float*)d_in[1];   // [8,2048,2048]
    float* out = (float*)d_out;                 // [8,512,2048]
    char* ws = (char*)d_ws;

    float2* xquad  = (float2*)(ws + XQ_OFF);
    float2* xtail  = (float2*)(ws + XTAIL_OFF);
    float*  pxx    = (float*)(ws + PXX_OFF);
    float*  scores = (float*)(ws + SCORES_OFF);
    int*    topk   = (int*)(ws + TOPK_OFF);
    float*  wtab   = (float*)(ws + WTAB_OFF);
    float2* wrot   = (float2*)(ws + WROT_OFF);

    hipLaunchKernelGGL(k_xspec,  dim3(BQ * CQ),      dim3(256), 0, stream, tgt, xquad, xtail, pxx, wtab, wrot);
    hipLaunchKernelGGL(k_score,  dim3(BQ * NQ),      dim3(256), 0, stream, db, xquad, xtail, pxx, wtab, wrot, scores);
    hipLaunchKernelGGL(k_topk,   dim3(BQ * CQ),      dim3(256), 0, stream, scores, topk);
    hipLaunchKernelGGL(k_gather, dim3(BQ * CQ * KQ), dim3(256), 0, stream, db, topk, out);
}

// Round 10
// 423.990 us; speedup vs baseline: 1.0657x; 1.0657x over previous
//
#include <hip/hip_runtime.h>

// Problem constants
#define BQ 8
#define CQ 16
#define LQ 2048
#define NQ 2048
#define NPS 128      // nperseg
#define STEPQ 64     // step (50% overlap)
#define SQ 31        // segments per series
#define FQ 65        // rfft bins
#define KQ 32        // nref
#define EPSQ 1e-12f

// ---- workspace layout (bytes) ----
#define XQ_OFF     0ull
#define XTAIL_OFF  2031616ull
#define PXX_OFF    2063360ull                    // float [B][C][F] = 8320 floats
#define SCORES_OFF 2096640ull                    // float [B][C][N] = 262144 floats
#define TOPK_OFF   3145216ull                    // int [B][C][K] = 8192 ints
#define WTAB_OFF   3177984ull                    // float[128] Hann window (ends 3178496)

// ---- shared memory layout (float offsets) ----
// Y rows: float2 [31][YLD], bins 0..64 at natural columns, YLD=66 keeps the
// score-loop reads 16B-aligned (2x ds_read_b128 per s-iter — the hot path).
#define YLD 66
#define OFF_Y     0                              // float2[31*66] = 4092 floats
#define OFF_PYY   4092                           // 65
#define OFF_RED   4157                           // 256
#define SMEM_FLOATS 4413                         // 17652 B -> 8 blocks/CU (wave-capped)

// compile-time {cos(2pi j/16), -sin(2pi j/16)} pairs (j folded constant after unroll)
#define C16R(j) ((j)==0?1.0f:(j)==1?0.92387953251128675613f:(j)==2?0.70710678118654752440f:\
    (j)==3?0.38268343236508977173f:(j)==4?0.0f:(j)==5?-0.38268343236508977173f:\
    (j)==6?-0.70710678118654752440f:(j)==7?-0.92387953251128675613f:(j)==8?-1.0f:\
    (j)==9?-0.92387953251128675613f:(j)==10?-0.70710678118654752440f:(j)==11?-0.38268343236508977173f:\
    (j)==12?0.0f:(j)==13?0.38268343236508977173f:(j)==14?0.70710678118654752440f:0.92387953251128675613f)
#define C16I(j) (-((j)==0?0.0f:(j)==1?0.38268343236508977173f:(j)==2?0.70710678118654752440f:\
    (j)==3?0.92387953251128675613f:(j)==4?1.0f:(j)==5?0.92387953251128675613f:\
    (j)==6?0.70710678118654752440f:(j)==7?0.38268343236508977173f:(j)==8?0.0f:\
    (j)==9?-0.38268343236508977173f:(j)==10?-0.70710678118654752440f:(j)==11?-0.92387953251128675613f:\
    (j)==12?-1.0f:(j)==13?-0.92387953251128675613f:(j)==14?-0.70710678118654752440f:-0.38268343236508977173f))

// stage-A butterfly twiddles W8^{t1-4} for t1>=4, identity for t1<4
__device__ __constant__ const float WA_R[8] = {1.f, 1.f, 1.f, 1.f,
    1.f, 0.70710678118654752440f, 0.f, -0.70710678118654752440f};
__device__ __constant__ const float WA_I[8] = {0.f, 0.f, 0.f, 0.f,
    0.f, -0.70710678118654752440f, -1.f, -0.70710678118654752440f};
__device__ __constant__ const int BR3_[8] = {0, 4, 2, 6, 1, 5, 3, 7};

#define TWOPI_128 0.049087385212340519350978802863742f   // 2*pi/128

// ---- DPP lane-xor (all on the VALU pipe — no LDS-pipe cross-lane ops) ----
__device__ __forceinline__ float dppx1(float v) {   // lane ^ 1: quad_perm [1,0,3,2] = 0xB1
    return __int_as_float(__builtin_amdgcn_update_dpp(0, __float_as_int(v), 0xB1, 0xF, 0xF, true));
}
__device__ __forceinline__ float dppx2(float v) {   // lane ^ 2: quad_perm [2,3,0,1] = 0x4E
    return __int_as_float(__builtin_amdgcn_update_dpp(0, __float_as_int(v), 0x4E, 0xF, 0xF, true));
}
__device__ __forceinline__ float dppx8(float v) {   // lane ^ 8: row_ror:8 = 0x128 (16-row)
    return __int_as_float(__builtin_amdgcn_update_dpp(0, __float_as_int(v), 0x128, 0xF, 0xF, true));
}

// ---- VOP3P packed-fp32 helpers (proven) ----
// complex X*conj(Y) accumulate, acc={pr,pi}, x={xr,xi}, y={yr,yi}:
__device__ __forceinline__ float2 pk_cma1(float2 x, float2 y, float2 acc) {
    float2 d;
    asm("v_pk_fma_f32 %0, %1, %2, %3 op_sel:[0,0,0] op_sel_hi:[1,0,1]"
        : "=v"(d) : "v"(x), "v"(y), "v"(acc));
    return d;
}
__device__ __forceinline__ float2 pk_cma2(float2 x, float2 y, float2 acc) {
    float2 d;
    asm("v_pk_fma_f32 %0, %1, %2, %3 op_sel:[1,1,0] op_sel_hi:[0,1,1] neg_hi:[1,0,0]"
        : "=v"(d) : "v"(x), "v"(y), "v"(acc));
    return d;
}
// stage-1 DFT: g += x_lo * {cos,-sin}  (a broadcasts lo/hi half; b = SGPR-pair constant)
__device__ __forceinline__ float2 pk_dft_lo(float2 xp, float2 w, float2 g) {
    float2 d;
    asm("v_pk_fma_f32 %0, %1, %2, %3 op_sel:[0,0,0] op_sel_hi:[0,1,1]"
        : "=v"(d) : "v"(xp), "s"(w), "v"(g));
    return d;
}
__device__ __forceinline__ float2 pk_dft_hi(float2 xp, float2 w, float2 g) {
    float2 d;
    asm("v_pk_fma_f32 %0, %1, %2, %3 op_sel:[1,0,0] op_sel_hi:[1,1,1]"
        : "=v"(d) : "v"(xp), "s"(w), "v"(g));
    return d;
}

// Welch spectra of one length-2048 row into smem Y (float2 [31][YLD], cols 0..64).
// Scalar butterfly arithmetic: bitwise-identical to the proven kernel.
// LANE REMAP (r8, proven +8µs): t1 bit2 lives on lane bit3, so ALL cross-lane
// exchanges are DPP (stage A xor-t1bit2 = lane^8 = row_ror:8; stages B/C =
// quad_perm) — no LDS-pipe cross-lane ops. H-twiddle stays as the register-only
// rotation chain (r9 proved a table load in this serial loop costs −41µs).
// Writes pair-combined into ds_write_b128 (odd mp), single b64 for bin 64.
template<bool TAB>
__device__ __forceinline__ void welch_spectra(const float* __restrict__ grow,
                                              const float* __restrict__ wtab,
                                              float* smem) {
    const int tid = threadIdx.x;
    float2* s_y = (float2*)(smem + OFF_Y);

    const int lane = tid & 63;
    const int t1 = (lane & 3) | ((lane >> 1) & 4);                 // t1 bit2 <- lane bit3
    const int s  = ((tid >> 6) << 3) | ((lane >> 3) & 6) | ((lane >> 2) & 1);
    const bool act = s < SQ;

    float x[16];
    float sum = 0.f;
    if (act) {
        const float* rp = grow + s * STEPQ + t1;
#pragma unroll
        for (int t2 = 0; t2 < 16; ++t2) x[t2] = rp[8 * t2];
#pragma unroll
        for (int t2 = 0; t2 < 16; ++t2) sum += x[t2];
    }
    // segment mean across the 8 t1-lanes (partners: lane^1, lane^2, lane^8 — same s)
    sum += dppx1(sum);
    sum += dppx2(sum);
    sum += dppx8(sum);
    const float mean = sum * (1.0f / 128.0f);

    float2 G[9];
    if (act) {
        float2 xp[8];
#pragma unroll
        for (int t2 = 0; t2 < 16; ++t2) {
            float wv;
            if (TAB) {
                wv = wtab[t1 + 8 * t2];                       // L1-resident, bitwise == inline cos
            } else {
                const float a = (float)(t1 + 8 * t2) * TWOPI_128;
                wv = 0.5f - 0.5f * __cosf(a);
            }
            x[t2] = (x[t2] - mean) * wv;
        }
#pragma unroll
        for (int j = 0; j < 8; ++j) xp[j] = make_float2(x[2 * j], x[2 * j + 1]);
#pragma unroll
        for (int m = 0; m < 9; ++m) {
            float2 g = make_float2(0.f, 0.f);
#pragma unroll
            for (int j = 0; j < 8; ++j) {
                {
                    const int i0 = (m * (2 * j)) & 15;
                    g = pk_dft_lo(xp[j], make_float2(C16R(i0), C16I(i0)), g);
                }
                {
                    const int i1 = (m * (2 * j + 1)) & 15;
                    g = pk_dft_hi(xp[j], make_float2(C16R(i1), C16I(i1)), g);
                }
            }
            G[m] = g;
        }
    }

    // per-lane butterfly constants
    const float s1 = (t1 & 4) ? -1.f : 1.f;
    const float s2 = (t1 & 2) ? -1.f : 1.f;
    const float s3 = (t1 & 1) ? -1.f : 1.f;
    const float war = WA_R[t1], wai = WA_I[t1];
    const bool q3 = (t1 & 3) == 3;
    const int kbase = 16 * BR3_[t1];          // lane t1 owns bins kbase..kbase+15

    // incremental H-twiddle rotation: w(m') = e^{-2pi i t1 m'/128}
    float cr, ci;
    __sincosf((float)t1 * TWOPI_128, &ci, &cr);   // ci=sin, cr=cos
    ci = -ci;
    float wr = 1.f, wi = 0.f;

    if (act) {
        float2* yrow = s_y + s * YLD + kbase;
        float2 vprev = make_float2(0.f, 0.f);
#pragma unroll
        for (int mp = 0; mp < 16; ++mp) {
            const int mm = (mp <= 8) ? mp : 16 - mp;
            const float sg = (mp <= 8) ? 1.f : -1.f;   // conj(G) for m'>8 (real input)
            const float gr = G[mm].x, gi = sg * G[mm].y;
            float hr = wr * gr - wi * gi;
            float hi = wr * gi + wi * gr;
            // stage A: xor t1-bit2 (= lane^8, DPP row_ror:8), twiddle W8^{t1-4} on upper lanes
            float orr = dppx8(hr), oi = dppx8(hi);
            float vr = fmaf(s1, hr, orr), vi = fmaf(s1, hi, oi);
            hr = vr * war - vi * wai;
            hi = vr * wai + vi * war;
            // stage B: xor 2 (DPP), twiddle -i on q==3 lanes
            orr = dppx2(hr); oi = dppx2(hi);
            vr = fmaf(s2, hr, orr); vi = fmaf(s2, hi, oi);
            hr = q3 ? vi : vr;
            hi = q3 ? -vr : vi;
            // stage C: xor 1 (DPP)
            orr = dppx1(hr); oi = dppx1(hi);
            vr = fmaf(s3, hr, orr); vi = fmaf(s3, hi, oi);
            if (mp & 1) {
                if (kbase + mp <= 64) {            // both bins of pair valid (br3<=3)
                    float4 w4 = make_float4(vprev.x, vprev.y, vr, vi);
                    *(float4*)(yrow + (mp - 1)) = w4;          // ds_write_b128, 16B-aligned
                } else if (kbase + mp == 65) {     // br3==4, mp==1: only bin 64 valid
                    yrow[0] = vprev;                           // single b64 (vprev = bin 64)
                }
            } else {
                vprev = make_float2(vr, vi);
            }
            // rotate twiddle
            const float nwr = wr * cr - wi * ci;
            wi = wr * ci + wi * cr;
            wr = nwr;
        }
    }
    __syncthreads();
}

// Target spectra: one block per (b,c). Writes xquad/xtail and Pxx [B][C][F].
// Block 0 also materializes the Hann window table for k_score.
__global__ __launch_bounds__(256) void k_xspec(const float* __restrict__ tgt,
                                               float2* __restrict__ xquad,
                                               float2* __restrict__ xtail,
                                               float* __restrict__ pxx,
                                               float* __restrict__ wtab) {
    __shared__ float smem[SMEM_FLOATS];
    const int blk = blockIdx.x;            // b*16 + c
    const int b = blk >> 4, c = blk & 15;
    const int tid = threadIdx.x;
    if (blk == 0 && tid < NPS)
        wtab[tid] = 0.5f - 0.5f * __cosf((float)tid * TWOPI_128);
    welch_spectra<false>(tgt + (size_t)blk * LQ, nullptr, smem);
    const float2* s_y = (const float2*)(smem + OFF_Y);
    for (int i = tid; i < SQ * FQ; i += 256) {
        const int s2 = i / 65, k = i - 65 * s2;
        const float2 v = s_y[s2 * YLD + k];
        if (k < 64) {
            const int q = k >> 2, j = k & 3;
            xquad[((((size_t)b * 16 + q) * SQ + s2) * CQ + c) * 4 + j] = v;
        } else {
            xtail[((size_t)b * SQ + s2) * CQ + c] = v;
        }
    }
    if (tid < FQ) {
        float a = 0.f;
        for (int s = 0; s < SQ; ++s) {
            const float2 y = s_y[s * YLD + tid];
            a += y.x * y.x + y.y * y.y;
        }
        pxx[(size_t)blk * FQ + tid] = a * (1.0f / (float)SQ);
    }
}

// exact pk sequence of the proven kernel, as a macro so the pipeline can reuse it
#define SCORE_COMPUTE(XA, XB, YA, YB)                                            \
    do {                                                                         \
        const float2 x0 = make_float2((XA).x, (XA).y), x1 = make_float2((XA).z, (XA).w); \
        const float2 x2 = make_float2((XB).x, (XB).y), x3 = make_float2((XB).z, (XB).w); \
        const float2 y0 = make_float2((YA).x, (YA).y), y1 = make_float2((YA).z, (YA).w); \
        const float2 y2 = make_float2((YB).x, (YB).y), y3 = make_float2((YB).z, (YB).w); \
        a0 = pk_cma1(x0, y0, a0);  a0 = pk_cma2(x0, y0, a0);                     \
        a1 = pk_cma1(x1, y1, a1);  a1 = pk_cma2(x1, y1, a1);                     \
        a2 = pk_cma1(x2, y2, a2);  a2 = pk_cma2(x2, y2, a2);                     \
        a3 = pk_cma1(x3, y3, a3);  a3 = pk_cma2(x3, y3, a3);                     \
    } while (0)

// Score: one block per (b,n). Y spectra, Pyy, coherence vs 16 channels (packed fp32).
// Score loop is software-pipelined (depth 1): loads for s+1 issue before compute
// of s, giving each LDS (~120cy) / L2 (~200cy) load a full iteration of cover.
// (Depth-2, asymmetric, and full-unroll variants all collapsed in r5-r7 —
// depth-1 @ VGPR 40 is the stable optimum of this axis.)
__global__ __launch_bounds__(256) void k_score(const float* __restrict__ db,
                                               const float2* __restrict__ xquad,
                                               const float2* __restrict__ xtail,
                                               const float* __restrict__ pxx,
                                               const float* __restrict__ wtab,
                                               float* __restrict__ scores) {
    __shared__ float smem[SMEM_FLOATS];
    const int blk = blockIdx.x;            // b*2048 + n
    const int b = blk >> 11, n = blk & 2047;
    welch_spectra<true>(db + (size_t)blk * LQ, wtab, smem);
    float* s_pyy = smem + OFF_PYY;
    float* s_red = smem + OFF_RED;
    const int tid = threadIdx.x;

    if (tid < FQ) {
        float a = 0.f;
        for (int s = 0; s < SQ; ++s) {
            const float2 y = ((const float2*)(smem + OFF_Y))[s * YLD + tid];
            a += y.x * y.x + y.y * y.y;
        }
        s_pyy[tid] = a * (1.0f / (float)SQ);
    }
    __syncthreads();

    const int c = tid & 15, g = tid >> 4;
    const int f0 = 4 * g;
    // x quad pointer for (b, q=g, c): 2 float4 per (s,c); stride per s = 32 float4
    const float4* xp = (const float4*)xquad + (((size_t)(b * 16 + g) * SQ) * CQ + c) * 2;
    const float*  px = pxx + ((size_t)b * CQ + c) * FQ;
    const float*  ybase = smem + OFF_Y;
#define YADDR(S) ((const float4*)(ybase + (size_t)((S) * YLD + f0) * 2))

    float2 a0 = make_float2(0.f, 0.f), a1 = a0, a2 = a0, a3 = a0;   // {pr,pi}

    // prologue: s = 0 in flight
    float4 xa = xp[0], xb4 = xp[1];
    xp += 32;
    float4 ya = YADDR(0)[0], yb = YADDR(0)[1];

#pragma unroll 2
    for (int s = 0; s < SQ - 1; ++s) {      // s = 0..29; prefetch s+1 before compute
        const float4 xa_n = xp[0], xb_n = xp[1];
        xp += 32;
        const float4 ya_n = YADDR(s + 1)[0], yb_n = YADDR(s + 1)[1];
        SCORE_COMPUTE(xa, xb4, ya, yb);
        xa = xa_n; xb4 = xb_n; ya = ya_n; yb = yb_n;
    }
    SCORE_COMPUTE(xa, xb4, ya, yb);         // s = 30
#undef YADDR

    const float invS2 = 1.0f / ((float)SQ * (float)SQ);
    float acc = 0.f;
    acc += ((a0.x * a0.x + a0.y * a0.y) * invS2) / (px[f0 + 0] * s_pyy[f0 + 0] + EPSQ);
    acc += ((a1.x * a1.x + a1.y * a1.y) * invS2) / (px[f0 + 1] * s_pyy[f0 + 1] + EPSQ);
    acc += ((a2.x * a2.x + a2.y * a2.y) * invS2) / (px[f0 + 2] * s_pyy[f0 + 2] + EPSQ);
    acc += ((a3.x * a3.x + a3.y * a3.y) * invS2) / (px[f0 + 3] * s_pyy[f0 + 3] + EPSQ);

    if (g == 0) {                            // bin 64 tail, 16 threads
        float2 a4 = make_float2(0.f, 0.f);
        const float2* xt = xtail + (size_t)b * SQ * CQ + c;
        for (int s = 0; s < SQ; ++s) {
            const float2 y4 = ((const float2*)(smem + OFF_Y))[s * YLD + 64];
            const float2 x4 = xt[s * CQ];
            a4 = pk_cma1(x4, y4, a4);  a4 = pk_cma2(x4, y4, a4);
        }
        acc += ((a4.x * a4.x + a4.y * a4.y) * invS2) / (px[64] * s_pyy[64] + EPSQ);
    }

    s_red[tid] = acc;                       // tid = g*16 + c
    __syncthreads();
    if (tid < 16) {
        float a = 0.f;
#pragma unroll
        for (int gg = 0; gg < 16; ++gg) a += s_red[gg * 16 + tid];
        scores[((size_t)b * CQ + tid) * NQ + n] = a * (1.0f / (float)FQ);
    }
}

// Top-32 per (b,c) row, jax.lax.top_k semantics (desc, ties->lowest idx).
// Scores kept register-resident (8/thread); zap via static-index compare.
__global__ __launch_bounds__(256) void k_topk(const float* __restrict__ scores,
                                              int* __restrict__ topk) {
    __shared__ float rv[4];
    __shared__ int   ri[4];
    __shared__ int   sbj;
    const int blk = blockIdx.x, tid = threadIdx.x;
    const float* row = scores + (size_t)blk * NQ;
    float v[8];
#pragma unroll
    for (int j = 0; j < 8; ++j) v[j] = row[tid + 256 * j];
    for (int k = 0; k < KQ; ++k) {
        float best = -3.402823466e38f;
        int bi = 0x7fffffff;
#pragma unroll
        for (int j = 0; j < 8; ++j) {
            if (v[j] > best) { best = v[j]; bi = tid + 256 * j; }  // ascending idx: strict > keeps smallest
        }
#pragma unroll
        for (int off = 1; off < 64; off <<= 1) {
            const float ov = __shfl_xor(best, off, 64);
            const int   oi = __shfl_xor(bi, off, 64);
            if (ov > best || (ov == best && oi < bi)) { best = ov; bi = oi; }
        }
        if ((tid & 63) == 0) { rv[tid >> 6] = best; ri[tid >> 6] = bi; }
        __syncthreads();
        if (tid == 0) {
            float bv = rv[0]; int bj = ri[0];
#pragma unroll
            for (int w2 = 1; w2 < 4; ++w2) {
                if (rv[w2] > bv || (rv[w2] == bv && ri[w2] < bj)) { bv = rv[w2]; bj = ri[w2]; }
            }
            topk[blk * KQ + k] = bj;
            sbj = bj;
        }
        __syncthreads();
        const int bj = sbj;
#pragma unroll
        for (int j = 0; j < 8; ++j)
            if (bj == tid + 256 * j) v[j] = -3.402823466e38f;
    }
}

// Gather: one block per output row (b, c*32+k) -> copy DB row (2048 floats) via float4.
__global__ __launch_bounds__(256) void k_gather(const float* __restrict__ db,
                                                const int* __restrict__ topk,
                                                float* __restrict__ out) {
    const int row = blockIdx.x;               // b*512 + c*32 + k
    const int b = row >> 9;
    const int idx = topk[row];
    const float4* src = (const float4*)(db + ((size_t)(b * NQ + idx)) * LQ);
    float4* dst = (float4*)(out + (size_t)row * LQ);
    const int tid = threadIdx.x;
    dst[tid] = src[tid];
    dst[tid + 256] = src[tid + 256];
}

extern "C" void kernel_launch(void* const* d_in, const int* in_sizes, int n_in,
                              void* d_out, int out_size, void* d_ws, size_t ws_size,
                              hipStream_t stream) {
    const float* tgt = (const float*)d_in[0];   // [8,16,2048]
    const float* db  = (const float*)d_in[1];   // [8,2048,2048]
    float* out = (float*)d_out;                 // [8,512,2048]
    char* ws = (char*)d_ws;

    float2* xquad  = (float2*)(ws + XQ_OFF);
    float2* xtail  = (float2*)(ws + XTAIL_OFF);
    float*  pxx    = (float*)(ws + PXX_OFF);
    float*  scores = (float*)(ws + SCORES_OFF);
    int*    topk   = (int*)(ws + TOPK_OFF);
    float*  wtab   = (float*)(ws + WTAB_OFF);

    hipLaunchKernelGGL(k_xspec,  dim3(BQ * CQ),      dim3(256), 0, stream, tgt, xquad, xtail, pxx, wtab);
    hipLaunchKernelGGL(k_score,  dim3(BQ * NQ),      dim3(256), 0, stream, db, xquad, xtail, pxx, wtab, scores);
    hipLaunchKernelGGL(k_topk,   dim3(BQ * CQ),      dim3(256), 0, stream, scores, topk);
    hipLaunchKernelGGL(k_gather, dim3(BQ * CQ * KQ), dim3(256), 0, stream, db, topk, out);
}

// Round 11
// 418.481 us; speedup vs baseline: 1.0797x; 1.0132x over previous
//
#include <hip/hip_runtime.h>

// Problem constants
#define BQ 8
#define CQ 16
#define LQ 2048
#define NQ 2048
#define NPS 128      // nperseg
#define STEPQ 64     // step (50% overlap)
#define SQ 31        // segments per series
#define FQ 65        // rfft bins
#define KQ 32        // nref
#define EPSQ 1e-12f

// ---- workspace layout (bytes) ----
#define XQ_OFF     0ull
#define XTAIL_OFF  2031616ull
#define PXX_OFF    2063360ull                    // float [B][C][F] = 8320 floats
#define SCORES_OFF 2096640ull                    // float [B][C][N] = 262144 floats
#define WTAB_OFF   3177984ull                    // float[128] Hann window (ends 3178496)

// ---- shared memory layout (float offsets) ----
// Y rows: float2 [31][YLD], bins 0..64 at natural columns, YLD=66 keeps the
// score-loop reads 16B-aligned (2x ds_read_b128 per s-iter — the hot path).
#define YLD 66
#define OFF_Y     0                              // float2[31*66] = 4092 floats
#define OFF_PYY   4092                           // 65
#define OFF_RED   4157                           // 256
#define SMEM_FLOATS 4413                         // 17652 B -> 8 blocks/CU (wave-capped)

// compile-time {cos(2pi j/16), -sin(2pi j/16)} pairs (j folded constant after unroll)
#define C16R(j) ((j)==0?1.0f:(j)==1?0.92387953251128675613f:(j)==2?0.70710678118654752440f:\
    (j)==3?0.38268343236508977173f:(j)==4?0.0f:(j)==5?-0.38268343236508977173f:\
    (j)==6?-0.70710678118654752440f:(j)==7?-0.92387953251128675613f:(j)==8?-1.0f:\
    (j)==9?-0.92387953251128675613f:(j)==10?-0.70710678118654752440f:(j)==11?-0.38268343236508977173f:\
    (j)==12?0.0f:(j)==13?0.38268343236508977173f:(j)==14?0.70710678118654752440f:0.92387953251128675613f)
#define C16I(j) (-((j)==0?0.0f:(j)==1?0.38268343236508977173f:(j)==2?0.70710678118654752440f:\
    (j)==3?0.92387953251128675613f:(j)==4?1.0f:(j)==5?0.92387953251128675613f:\
    (j)==6?0.70710678118654752440f:(j)==7?0.38268343236508977173f:(j)==8?0.0f:\
    (j)==9?-0.38268343236508977173f:(j)==10?-0.70710678118654752440f:(j)==11?-0.92387953251128675613f:\
    (j)==12?-1.0f:(j)==13?-0.92387953251128675613f:(j)==14?-0.70710678118654752440f:-0.38268343236508977173f))

// stage-A butterfly twiddles W8^{t1-4} for t1>=4, identity for t1<4
__device__ __constant__ const float WA_R[8] = {1.f, 1.f, 1.f, 1.f,
    1.f, 0.70710678118654752440f, 0.f, -0.70710678118654752440f};
__device__ __constant__ const float WA_I[8] = {0.f, 0.f, 0.f, 0.f,
    0.f, -0.70710678118654752440f, -1.f, -0.70710678118654752440f};
__device__ __constant__ const int BR3_[8] = {0, 4, 2, 6, 1, 5, 3, 7};

#define TWOPI_128 0.049087385212340519350978802863742f   // 2*pi/128

// ---- DPP lane-xor (all on the VALU pipe — no LDS-pipe cross-lane ops) ----
__device__ __forceinline__ float dppx1(float v) {   // lane ^ 1: quad_perm [1,0,3,2] = 0xB1
    return __int_as_float(__builtin_amdgcn_update_dpp(0, __float_as_int(v), 0xB1, 0xF, 0xF, true));
}
__device__ __forceinline__ float dppx2(float v) {   // lane ^ 2: quad_perm [2,3,0,1] = 0x4E
    return __int_as_float(__builtin_amdgcn_update_dpp(0, __float_as_int(v), 0x4E, 0xF, 0xF, true));
}
__device__ __forceinline__ float dppx8(float v) {   // lane ^ 8: row_ror:8 = 0x128 (16-row)
    return __int_as_float(__builtin_amdgcn_update_dpp(0, __float_as_int(v), 0x128, 0xF, 0xF, true));
}

// ---- VOP3P packed-fp32 helpers (proven) ----
// complex X*conj(Y) accumulate, acc={pr,pi}, x={xr,xi}, y={yr,yi}:
__device__ __forceinline__ float2 pk_cma1(float2 x, float2 y, float2 acc) {
    float2 d;
    asm("v_pk_fma_f32 %0, %1, %2, %3 op_sel:[0,0,0] op_sel_hi:[1,0,1]"
        : "=v"(d) : "v"(x), "v"(y), "v"(acc));
    return d;
}
__device__ __forceinline__ float2 pk_cma2(float2 x, float2 y, float2 acc) {
    float2 d;
    asm("v_pk_fma_f32 %0, %1, %2, %3 op_sel:[1,1,0] op_sel_hi:[0,1,1] neg_hi:[1,0,0]"
        : "=v"(d) : "v"(x), "v"(y), "v"(acc));
    return d;
}
// stage-1 DFT: g += x_lo * {cos,-sin}  (a broadcasts lo/hi half; b = SGPR-pair constant)
__device__ __forceinline__ float2 pk_dft_lo(float2 xp, float2 w, float2 g) {
    float2 d;
    asm("v_pk_fma_f32 %0, %1, %2, %3 op_sel:[0,0,0] op_sel_hi:[0,1,1]"
        : "=v"(d) : "v"(xp), "s"(w), "v"(g));
    return d;
}
__device__ __forceinline__ float2 pk_dft_hi(float2 xp, float2 w, float2 g) {
    float2 d;
    asm("v_pk_fma_f32 %0, %1, %2, %3 op_sel:[1,0,0] op_sel_hi:[1,1,1]"
        : "=v"(d) : "v"(xp), "s"(w), "v"(g));
    return d;
}

// Welch spectra of one length-2048 row into smem Y (float2 [31][YLD], cols 0..64).
// Scalar butterfly arithmetic: bitwise-identical to the proven kernel.
// LANE REMAP (r8, proven +8µs): t1 bit2 lives on lane bit3, so ALL cross-lane
// exchanges are DPP (stage A xor-t1bit2 = lane^8 = row_ror:8; stages B/C =
// quad_perm) — no LDS-pipe cross-lane ops. H-twiddle stays as the register-only
// rotation chain (r9 proved a table load in this serial loop costs −41µs).
// Writes pair-combined into ds_write_b128 (odd mp), single b64 for bin 64.
template<bool TAB>
__device__ __forceinline__ void welch_spectra(const float* __restrict__ grow,
                                              const float* __restrict__ wtab,
                                              float* smem) {
    const int tid = threadIdx.x;
    float2* s_y = (float2*)(smem + OFF_Y);

    const int lane = tid & 63;
    const int t1 = (lane & 3) | ((lane >> 1) & 4);                 // t1 bit2 <- lane bit3
    const int s  = ((tid >> 6) << 3) | ((lane >> 3) & 6) | ((lane >> 2) & 1);
    const bool act = s < SQ;

    float x[16];
    float sum = 0.f;
    if (act) {
        const float* rp = grow + s * STEPQ + t1;
#pragma unroll
        for (int t2 = 0; t2 < 16; ++t2) x[t2] = rp[8 * t2];
#pragma unroll
        for (int t2 = 0; t2 < 16; ++t2) sum += x[t2];
    }
    // segment mean across the 8 t1-lanes (partners: lane^1, lane^2, lane^8 — same s)
    sum += dppx1(sum);
    sum += dppx2(sum);
    sum += dppx8(sum);
    const float mean = sum * (1.0f / 128.0f);

    float2 G[9];
    if (act) {
        float2 xp[8];
#pragma unroll
        for (int t2 = 0; t2 < 16; ++t2) {
            float wv;
            if (TAB) {
                wv = wtab[t1 + 8 * t2];                       // L1-resident, bitwise == inline cos
            } else {
                const float a = (float)(t1 + 8 * t2) * TWOPI_128;
                wv = 0.5f - 0.5f * __cosf(a);
            }
            x[t2] = (x[t2] - mean) * wv;
        }
#pragma unroll
        for (int j = 0; j < 8; ++j) xp[j] = make_float2(x[2 * j], x[2 * j + 1]);
#pragma unroll
        for (int m = 0; m < 9; ++m) {
            float2 g = make_float2(0.f, 0.f);
#pragma unroll
            for (int j = 0; j < 8; ++j) {
                {
                    const int i0 = (m * (2 * j)) & 15;
                    g = pk_dft_lo(xp[j], make_float2(C16R(i0), C16I(i0)), g);
                }
                {
                    const int i1 = (m * (2 * j + 1)) & 15;
                    g = pk_dft_hi(xp[j], make_float2(C16R(i1), C16I(i1)), g);
                }
            }
            G[m] = g;
        }
    }

    // per-lane butterfly constants
    const float s1 = (t1 & 4) ? -1.f : 1.f;
    const float s2 = (t1 & 2) ? -1.f : 1.f;
    const float s3 = (t1 & 1) ? -1.f : 1.f;
    const float war = WA_R[t1], wai = WA_I[t1];
    const bool q3 = (t1 & 3) == 3;
    const int kbase = 16 * BR3_[t1];          // lane t1 owns bins kbase..kbase+15

    // incremental H-twiddle rotation: w(m') = e^{-2pi i t1 m'/128}
    float cr, ci;
    __sincosf((float)t1 * TWOPI_128, &ci, &cr);   // ci=sin, cr=cos
    ci = -ci;
    float wr = 1.f, wi = 0.f;

    if (act) {
        float2* yrow = s_y + s * YLD + kbase;
        float2 vprev = make_float2(0.f, 0.f);
#pragma unroll
        for (int mp = 0; mp < 16; ++mp) {
            const int mm = (mp <= 8) ? mp : 16 - mp;
            const float sg = (mp <= 8) ? 1.f : -1.f;   // conj(G) for m'>8 (real input)
            const float gr = G[mm].x, gi = sg * G[mm].y;
            float hr = wr * gr - wi * gi;
            float hi = wr * gi + wi * gr;
            // stage A: xor t1-bit2 (= lane^8, DPP row_ror:8), twiddle W8^{t1-4} on upper lanes
            float orr = dppx8(hr), oi = dppx8(hi);
            float vr = fmaf(s1, hr, orr), vi = fmaf(s1, hi, oi);
            hr = vr * war - vi * wai;
            hi = vr * wai + vi * war;
            // stage B: xor 2 (DPP), twiddle -i on q==3 lanes
            orr = dppx2(hr); oi = dppx2(hi);
            vr = fmaf(s2, hr, orr); vi = fmaf(s2, hi, oi);
            hr = q3 ? vi : vr;
            hi = q3 ? -vr : vi;
            // stage C: xor 1 (DPP)
            orr = dppx1(hr); oi = dppx1(hi);
            vr = fmaf(s3, hr, orr); vi = fmaf(s3, hi, oi);
            if (mp & 1) {
                if (kbase + mp <= 64) {            // both bins of pair valid (br3<=3)
                    float4 w4 = make_float4(vprev.x, vprev.y, vr, vi);
                    *(float4*)(yrow + (mp - 1)) = w4;          // ds_write_b128, 16B-aligned
                } else if (kbase + mp == 65) {     // br3==4, mp==1: only bin 64 valid
                    yrow[0] = vprev;                           // single b64 (vprev = bin 64)
                }
            } else {
                vprev = make_float2(vr, vi);
            }
            // rotate twiddle
            const float nwr = wr * cr - wi * ci;
            wi = wr * ci + wi * cr;
            wr = nwr;
        }
    }
    __syncthreads();
}

// Target spectra: one block per (b,c). Writes xquad/xtail and Pxx [B][C][F].
// Block 0 also materializes the Hann window table for k_score.
__global__ __launch_bounds__(256) void k_xspec(const float* __restrict__ tgt,
                                               float2* __restrict__ xquad,
                                               float2* __restrict__ xtail,
                                               float* __restrict__ pxx,
                                               float* __restrict__ wtab) {
    __shared__ float smem[SMEM_FLOATS];
    const int blk = blockIdx.x;            // b*16 + c
    const int b = blk >> 4, c = blk & 15;
    const int tid = threadIdx.x;
    if (blk == 0 && tid < NPS)
        wtab[tid] = 0.5f - 0.5f * __cosf((float)tid * TWOPI_128);
    welch_spectra<false>(tgt + (size_t)blk * LQ, nullptr, smem);
    const float2* s_y = (const float2*)(smem + OFF_Y);
    for (int i = tid; i < SQ * FQ; i += 256) {
        const int s2 = i / 65, k = i - 65 * s2;
        const float2 v = s_y[s2 * YLD + k];
        if (k < 64) {
            const int q = k >> 2, j = k & 3;
            xquad[((((size_t)b * 16 + q) * SQ + s2) * CQ + c) * 4 + j] = v;
        } else {
            xtail[((size_t)b * SQ + s2) * CQ + c] = v;
        }
    }
    if (tid < FQ) {
        float a = 0.f;
        for (int s = 0; s < SQ; ++s) {
            const float2 y = s_y[s * YLD + tid];
            a += y.x * y.x + y.y * y.y;
        }
        pxx[(size_t)blk * FQ + tid] = a * (1.0f / (float)SQ);
    }
}

// exact pk sequence of the proven kernel, as a macro so the pipeline can reuse it
#define SCORE_COMPUTE(XA, XB, YA, YB)                                            \
    do {                                                                         \
        const float2 x0 = make_float2((XA).x, (XA).y), x1 = make_float2((XA).z, (XA).w); \
        const float2 x2 = make_float2((XB).x, (XB).y), x3 = make_float2((XB).z, (XB).w); \
        const float2 y0 = make_float2((YA).x, (YA).y), y1 = make_float2((YA).z, (YA).w); \
        const float2 y2 = make_float2((YB).x, (YB).y), y3 = make_float2((YB).z, (YB).w); \
        a0 = pk_cma1(x0, y0, a0);  a0 = pk_cma2(x0, y0, a0);                     \
        a1 = pk_cma1(x1, y1, a1);  a1 = pk_cma2(x1, y1, a1);                     \
        a2 = pk_cma1(x2, y2, a2);  a2 = pk_cma2(x2, y2, a2);                     \
        a3 = pk_cma1(x3, y3, a3);  a3 = pk_cma2(x3, y3, a3);                     \
    } while (0)

// Score: one block per (b,n). Y spectra, Pyy, coherence vs 16 channels (packed fp32).
// Score loop is software-pipelined (depth 1): loads for s+1 issue before compute
// of s, giving each LDS (~120cy) / L2 (~200cy) load a full iteration of cover.
// (Depth-2, asymmetric, and full-unroll variants all collapsed in r5-r7 —
// depth-1 @ VGPR 40 is the stable optimum of this axis.)
__global__ __launch_bounds__(256) void k_score(const float* __restrict__ db,
                                               const float2* __restrict__ xquad,
                                               const float2* __restrict__ xtail,
                                               const float* __restrict__ pxx,
                                               const float* __restrict__ wtab,
                                               float* __restrict__ scores) {
    __shared__ float smem[SMEM_FLOATS];
    const int blk = blockIdx.x;            // b*2048 + n
    const int b = blk >> 11, n = blk & 2047;
    welch_spectra<true>(db + (size_t)blk * LQ, wtab, smem);
    float* s_pyy = smem + OFF_PYY;
    float* s_red = smem + OFF_RED;
    const int tid = threadIdx.x;

    if (tid < FQ) {
        float a = 0.f;
        for (int s = 0; s < SQ; ++s) {
            const float2 y = ((const float2*)(smem + OFF_Y))[s * YLD + tid];
            a += y.x * y.x + y.y * y.y;
        }
        s_pyy[tid] = a * (1.0f / (float)SQ);
    }
    __syncthreads();

    const int c = tid & 15, g = tid >> 4;
    const int f0 = 4 * g;
    // x quad pointer for (b, q=g, c): 2 float4 per (s,c); stride per s = 32 float4
    const float4* xp = (const float4*)xquad + (((size_t)(b * 16 + g) * SQ) * CQ + c) * 2;
    const float*  px = pxx + ((size_t)b * CQ + c) * FQ;
    const float*  ybase = smem + OFF_Y;
#define YADDR(S) ((const float4*)(ybase + (size_t)((S) * YLD + f0) * 2))

    float2 a0 = make_float2(0.f, 0.f), a1 = a0, a2 = a0, a3 = a0;   // {pr,pi}

    // prologue: s = 0 in flight
    float4 xa = xp[0], xb4 = xp[1];
    xp += 32;
    float4 ya = YADDR(0)[0], yb = YADDR(0)[1];

#pragma unroll 2
    for (int s = 0; s < SQ - 1; ++s) {      // s = 0..29; prefetch s+1 before compute
        const float4 xa_n = xp[0], xb_n = xp[1];
        xp += 32;
        const float4 ya_n = YADDR(s + 1)[0], yb_n = YADDR(s + 1)[1];
        SCORE_COMPUTE(xa, xb4, ya, yb);
        xa = xa_n; xb4 = xb_n; ya = ya_n; yb = yb_n;
    }
    SCORE_COMPUTE(xa, xb4, ya, yb);         // s = 30
#undef YADDR

    const float invS2 = 1.0f / ((float)SQ * (float)SQ);
    float acc = 0.f;
    acc += ((a0.x * a0.x + a0.y * a0.y) * invS2) / (px[f0 + 0] * s_pyy[f0 + 0] + EPSQ);
    acc += ((a1.x * a1.x + a1.y * a1.y) * invS2) / (px[f0 + 1] * s_pyy[f0 + 1] + EPSQ);
    acc += ((a2.x * a2.x + a2.y * a2.y) * invS2) / (px[f0 + 2] * s_pyy[f0 + 2] + EPSQ);
    acc += ((a3.x * a3.x + a3.y * a3.y) * invS2) / (px[f0 + 3] * s_pyy[f0 + 3] + EPSQ);

    if (g == 0) {                            // bin 64 tail, 16 threads
        float2 a4 = make_float2(0.f, 0.f);
        const float2* xt = xtail + (size_t)b * SQ * CQ + c;
        for (int s = 0; s < SQ; ++s) {
            const float2 y4 = ((const float2*)(smem + OFF_Y))[s * YLD + 64];
            const float2 x4 = xt[s * CQ];
            a4 = pk_cma1(x4, y4, a4);  a4 = pk_cma2(x4, y4, a4);
        }
        acc += ((a4.x * a4.x + a4.y * a4.y) * invS2) / (px[64] * s_pyy[64] + EPSQ);
    }

    s_red[tid] = acc;                       // tid = g*16 + c
    __syncthreads();
    if (tid < 16) {
        float a = 0.f;
#pragma unroll
        for (int gg = 0; gg < 16; ++gg) a += s_red[gg * 16 + tid];
        scores[((size_t)b * CQ + tid) * NQ + n] = a * (1.0f / (float)FQ);
    }
}

// Fused top-32 + gather: one block per (b,c) row. Selection loop is byte-identical
// to the proven k_topk (desc, ties->lowest idx; register-resident scores); the 32
// winning indices are kept in smem and the 32 output rows (8KB each) are copied
// in a bulk phase afterward — removes the k_gather launch and the topk[] global
// round-trip. Output addresses/values identical to the split version.
__global__ __launch_bounds__(256) void k_topk_gather(const float* __restrict__ scores,
                                                     const float* __restrict__ db,
                                                     float* __restrict__ out) {
    __shared__ float rv[4];
    __shared__ int   ri[4];
    __shared__ int   sbj;
    __shared__ int   sidx[KQ];
    const int blk = blockIdx.x, tid = threadIdx.x;   // blk = b*16 + c
    const int b = blk >> 4;
    const float* row = scores + (size_t)blk * NQ;
    float v[8];
#pragma unroll
    for (int j = 0; j < 8; ++j) v[j] = row[tid + 256 * j];
    for (int k = 0; k < KQ; ++k) {
        float best = -3.402823466e38f;
        int bi = 0x7fffffff;
#pragma unroll
        for (int j = 0; j < 8; ++j) {
            if (v[j] > best) { best = v[j]; bi = tid + 256 * j; }  // ascending idx: strict > keeps smallest
        }
#pragma unroll
        for (int off = 1; off < 64; off <<= 1) {
            const float ov = __shfl_xor(best, off, 64);
            const int   oi = __shfl_xor(bi, off, 64);
            if (ov > best || (ov == best && oi < bi)) { best = ov; bi = oi; }
        }
        if ((tid & 63) == 0) { rv[tid >> 6] = best; ri[tid >> 6] = bi; }
        __syncthreads();
        if (tid == 0) {
            float bv = rv[0]; int bj = ri[0];
#pragma unroll
            for (int w2 = 1; w2 < 4; ++w2) {
                if (rv[w2] > bv || (rv[w2] == bv && ri[w2] < bj)) { bv = rv[w2]; bj = ri[w2]; }
            }
            sidx[k] = bj;
            sbj = bj;
        }
        __syncthreads();
        const int bj = sbj;
#pragma unroll
        for (int j = 0; j < 8; ++j)
            if (bj == tid + 256 * j) v[j] = -3.402823466e38f;
    }
    // bulk gather: 32 rows x 2048 floats -> out rows blk*32 .. blk*32+31
    float4* dstbase = (float4*)(out + (size_t)blk * KQ * LQ);
#pragma unroll 4
    for (int r = 0; r < KQ; ++r) {
        const int idx = sidx[r];
        const float4* src = (const float4*)(db + ((size_t)(b * NQ + idx)) * LQ);
        float4* dst = dstbase + (size_t)r * (LQ / 4);
        dst[tid] = src[tid];
        dst[tid + 256] = src[tid + 256];
    }
}

extern "C" void kernel_launch(void* const* d_in, const int* in_sizes, int n_in,
                              void* d_out, int out_size, void* d_ws, size_t ws_size,
                              hipStream_t stream) {
    const float* tgt = (const float*)d_in[0];   // [8,16,2048]
    const float* db  = (const float*)d_in[1];   // [8,2048,2048]
    float* out = (float*)d_out;                 // [8,512,2048]
    char* ws = (char*)d_ws;

    float2* xquad  = (float2*)(ws + XQ_OFF);
    float2* xtail  = (float2*)(ws + XTAIL_OFF);
    float*  pxx    = (float*)(ws + PXX_OFF);
    float*  scores = (float*)(ws + SCORES_OFF);
    float*  wtab   = (float*)(ws + WTAB_OFF);

    hipLaunchKernelGGL(k_xspec,       dim3(BQ * CQ), dim3(256), 0, stream, tgt, xquad, xtail, pxx, wtab);
    hipLaunchKernelGGL(k_score,       dim3(BQ * NQ), dim3(256), 0, stream, db, xquad, xtail, pxx, wtab, scores);
    hipLaunchKernelGGL(k_topk_gather, dim3(BQ * CQ), dim3(256), 0, stream, scores, db, out);
}

// Round 12
// 407.403 us; speedup vs baseline: 1.1091x; 1.0272x over previous
//
#include <hip/hip_runtime.h>

// Problem constants
#define BQ 8
#define CQ 16
#define LQ 2048
#define NQ 2048
#define NPS 128      // nperseg
#define STEPQ 64     // step (50% overlap)
#define SQ 31        // segments per series
#define FQ 65        // rfft bins
#define KQ 32        // nref
#define EPSQ 1e-12f

// ---- workspace layout (bytes) ----
#define XQ_OFF     0ull
#define XTAIL_OFF  2031616ull
#define PXX_OFF    2063360ull                    // float [B][C][F] = 8320 floats
#define SCORES_OFF 2096640ull                    // float [B][C][N] = 262144 floats
#define WTAB_OFF   3177984ull                    // float[128] Hann window (ends 3178496)

// ---- shared memory layout (float offsets) ----
// Y rows: float2 [31][YLD], bins 0..64 at natural columns, YLD=66 keeps the
// score-loop reads 16B-aligned (2x ds_read_b128 per s-iter — the hot path).
#define YLD 66
#define OFF_Y     0                              // float2[31*66] = 4092 floats
#define OFF_PYY   4092                           // 65
#define OFF_RED   4157                           // 256
#define SMEM_FLOATS 4413                         // 17652 B -> 8 blocks/CU (wave-capped)

// compile-time {cos(2pi j/16), -sin(2pi j/16)} pairs (j folded constant after unroll)
#define C16R(j) ((j)==0?1.0f:(j)==1?0.92387953251128675613f:(j)==2?0.70710678118654752440f:\
    (j)==3?0.38268343236508977173f:(j)==4?0.0f:(j)==5?-0.38268343236508977173f:\
    (j)==6?-0.70710678118654752440f:(j)==7?-0.92387953251128675613f:(j)==8?-1.0f:\
    (j)==9?-0.92387953251128675613f:(j)==10?-0.70710678118654752440f:(j)==11?-0.38268343236508977173f:\
    (j)==12?0.0f:(j)==13?0.38268343236508977173f:(j)==14?0.70710678118654752440f:0.92387953251128675613f)
#define C16I(j) (-((j)==0?0.0f:(j)==1?0.38268343236508977173f:(j)==2?0.70710678118654752440f:\
    (j)==3?0.92387953251128675613f:(j)==4?1.0f:(j)==5?0.92387953251128675613f:\
    (j)==6?0.70710678118654752440f:(j)==7?0.38268343236508977173f:(j)==8?0.0f:\
    (j)==9?-0.38268343236508977173f:(j)==10?-0.70710678118654752440f:(j)==11?-0.92387953251128675613f:\
    (j)==12?-1.0f:(j)==13?-0.92387953251128675613f:(j)==14?-0.70710678118654752440f:-0.38268343236508977173f))

// stage-A butterfly twiddles W8^{t1-4} for t1>=4, identity for t1<4
__device__ __constant__ const float WA_R[8] = {1.f, 1.f, 1.f, 1.f,
    1.f, 0.70710678118654752440f, 0.f, -0.70710678118654752440f};
__device__ __constant__ const float WA_I[8] = {0.f, 0.f, 0.f, 0.f,
    0.f, -0.70710678118654752440f, -1.f, -0.70710678118654752440f};
__device__ __constant__ const int BR3_[8] = {0, 4, 2, 6, 1, 5, 3, 7};

#define TWOPI_128 0.049087385212340519350978802863742f   // 2*pi/128

// ---- DPP lane-xor (all on the VALU pipe — no LDS-pipe cross-lane ops) ----
__device__ __forceinline__ float dppx1(float v) {   // lane ^ 1: quad_perm [1,0,3,2] = 0xB1
    return __int_as_float(__builtin_amdgcn_update_dpp(0, __float_as_int(v), 0xB1, 0xF, 0xF, true));
}
__device__ __forceinline__ float dppx2(float v) {   // lane ^ 2: quad_perm [2,3,0,1] = 0x4E
    return __int_as_float(__builtin_amdgcn_update_dpp(0, __float_as_int(v), 0x4E, 0xF, 0xF, true));
}
__device__ __forceinline__ float dppx8(float v) {   // lane ^ 8: row_ror:8 = 0x128 (16-row)
    return __int_as_float(__builtin_amdgcn_update_dpp(0, __float_as_int(v), 0x128, 0xF, 0xF, true));
}

// ---- VOP3P packed-fp32 helpers (proven) ----
// complex X*conj(Y) accumulate, acc={pr,pi}, x={xr,xi}, y={yr,yi}:
__device__ __forceinline__ float2 pk_cma1(float2 x, float2 y, float2 acc) {
    float2 d;
    asm("v_pk_fma_f32 %0, %1, %2, %3 op_sel:[0,0,0] op_sel_hi:[1,0,1]"
        : "=v"(d) : "v"(x), "v"(y), "v"(acc));
    return d;
}
__device__ __forceinline__ float2 pk_cma2(float2 x, float2 y, float2 acc) {
    float2 d;
    asm("v_pk_fma_f32 %0, %1, %2, %3 op_sel:[1,1,0] op_sel_hi:[0,1,1] neg_hi:[1,0,0]"
        : "=v"(d) : "v"(x), "v"(y), "v"(acc));
    return d;
}
// stage-1 DFT: g += x_lo * {cos,-sin}  (a broadcasts lo/hi half; b = SGPR-pair constant)
__device__ __forceinline__ float2 pk_dft_lo(float2 xp, float2 w, float2 g) {
    float2 d;
    asm("v_pk_fma_f32 %0, %1, %2, %3 op_sel:[0,0,0] op_sel_hi:[0,1,1]"
        : "=v"(d) : "v"(xp), "s"(w), "v"(g));
    return d;
}
__device__ __forceinline__ float2 pk_dft_hi(float2 xp, float2 w, float2 g) {
    float2 d;
    asm("v_pk_fma_f32 %0, %1, %2, %3 op_sel:[1,0,0] op_sel_hi:[1,1,1]"
        : "=v"(d) : "v"(xp), "s"(w), "v"(g));
    return d;
}

// Welch spectra of one length-2048 row into smem Y (float2 [31][YLD], cols 0..64).
// Scalar butterfly arithmetic: bitwise-identical to the proven kernel.
// LANE REMAP (r8, proven +8µs): t1 bit2 lives on lane bit3, so ALL cross-lane
// exchanges are DPP — no LDS-pipe cross-lane ops. H-twiddle stays as the
// register-only rotation chain (r9: table load in this loop costs −41µs).
// TAB path wraps the DFT burst in s_setprio(1)/(0) — phase-staggered blocks on a
// CU (welch VALU-dense vs score-loop latency-bound) are the T5-paying regime.
// Writes pair-combined into ds_write_b128 (odd mp), single b64 for bin 64.
template<bool TAB>
__device__ __forceinline__ void welch_spectra(const float* __restrict__ grow,
                                              const float* __restrict__ wtab,
                                              float* smem) {
    const int tid = threadIdx.x;
    float2* s_y = (float2*)(smem + OFF_Y);

    const int lane = tid & 63;
    const int t1 = (lane & 3) | ((lane >> 1) & 4);                 // t1 bit2 <- lane bit3
    const int s  = ((tid >> 6) << 3) | ((lane >> 3) & 6) | ((lane >> 2) & 1);
    const bool act = s < SQ;

    float x[16];
    float sum = 0.f;
    if (act) {
        const float* rp = grow + s * STEPQ + t1;
#pragma unroll
        for (int t2 = 0; t2 < 16; ++t2) x[t2] = rp[8 * t2];
#pragma unroll
        for (int t2 = 0; t2 < 16; ++t2) sum += x[t2];
    }
    // segment mean across the 8 t1-lanes (partners: lane^1, lane^2, lane^8 — same s)
    sum += dppx1(sum);
    sum += dppx2(sum);
    sum += dppx8(sum);
    const float mean = sum * (1.0f / 128.0f);

    float2 G[9];
    if (act) {
        float2 xp[8];
#pragma unroll
        for (int t2 = 0; t2 < 16; ++t2) {
            float wv;
            if (TAB) {
                wv = wtab[t1 + 8 * t2];                       // L1-resident, bitwise == inline cos
            } else {
                const float a = (float)(t1 + 8 * t2) * TWOPI_128;
                wv = 0.5f - 0.5f * __cosf(a);
            }
            x[t2] = (x[t2] - mean) * wv;
        }
#pragma unroll
        for (int j = 0; j < 8; ++j) xp[j] = make_float2(x[2 * j], x[2 * j + 1]);
        if (TAB) __builtin_amdgcn_s_setprio(1);
#pragma unroll
        for (int m = 0; m < 9; ++m) {
            float2 g = make_float2(0.f, 0.f);
#pragma unroll
            for (int j = 0; j < 8; ++j) {
                {
                    const int i0 = (m * (2 * j)) & 15;
                    g = pk_dft_lo(xp[j], make_float2(C16R(i0), C16I(i0)), g);
                }
                {
                    const int i1 = (m * (2 * j + 1)) & 15;
                    g = pk_dft_hi(xp[j], make_float2(C16R(i1), C16I(i1)), g);
                }
            }
            G[m] = g;
        }
        if (TAB) __builtin_amdgcn_s_setprio(0);
    }

    // per-lane butterfly constants
    const float s1 = (t1 & 4) ? -1.f : 1.f;
    const float s2 = (t1 & 2) ? -1.f : 1.f;
    const float s3 = (t1 & 1) ? -1.f : 1.f;
    const float war = WA_R[t1], wai = WA_I[t1];
    const bool q3 = (t1 & 3) == 3;
    const int kbase = 16 * BR3_[t1];          // lane t1 owns bins kbase..kbase+15

    // incremental H-twiddle rotation: w(m') = e^{-2pi i t1 m'/128}
    float cr, ci;
    __sincosf((float)t1 * TWOPI_128, &ci, &cr);   // ci=sin, cr=cos
    ci = -ci;
    float wr = 1.f, wi = 0.f;

    if (act) {
        float2* yrow = s_y + s * YLD + kbase;
        float2 vprev = make_float2(0.f, 0.f);
#pragma unroll
        for (int mp = 0; mp < 16; ++mp) {
            const int mm = (mp <= 8) ? mp : 16 - mp;
            const float sg = (mp <= 8) ? 1.f : -1.f;   // conj(G) for m'>8 (real input)
            const float gr = G[mm].x, gi = sg * G[mm].y;
            float hr = wr * gr - wi * gi;
            float hi = wr * gi + wi * gr;
            // stage A: xor t1-bit2 (= lane^8, DPP row_ror:8), twiddle W8^{t1-4} on upper lanes
            float orr = dppx8(hr), oi = dppx8(hi);
            float vr = fmaf(s1, hr, orr), vi = fmaf(s1, hi, oi);
            hr = vr * war - vi * wai;
            hi = vr * wai + vi * war;
            // stage B: xor 2 (DPP), twiddle -i on q==3 lanes
            orr = dppx2(hr); oi = dppx2(hi);
            vr = fmaf(s2, hr, orr); vi = fmaf(s2, hi, oi);
            hr = q3 ? vi : vr;
            hi = q3 ? -vr : vi;
            // stage C: xor 1 (DPP)
            orr = dppx1(hr); oi = dppx1(hi);
            vr = fmaf(s3, hr, orr); vi = fmaf(s3, hi, oi);
            if (mp & 1) {
                if (kbase + mp <= 64) {            // both bins of pair valid (br3<=3)
                    float4 w4 = make_float4(vprev.x, vprev.y, vr, vi);
                    *(float4*)(yrow + (mp - 1)) = w4;          // ds_write_b128, 16B-aligned
                } else if (kbase + mp == 65) {     // br3==4, mp==1: only bin 64 valid
                    yrow[0] = vprev;                           // single b64 (vprev = bin 64)
                }
            } else {
                vprev = make_float2(vr, vi);
            }
            // rotate twiddle
            const float nwr = wr * cr - wi * ci;
            wi = wr * ci + wi * cr;
            wr = nwr;
        }
    }
    __syncthreads();
}

// Target spectra: one block per (b,c). Writes xquad/xtail and Pxx [B][C][F].
// Block 0 also materializes the Hann window table for k_score.
__global__ __launch_bounds__(256) void k_xspec(const float* __restrict__ tgt,
                                               float2* __restrict__ xquad,
                                               float2* __restrict__ xtail,
                                               float* __restrict__ pxx,
                                               float* __restrict__ wtab) {
    __shared__ float smem[SMEM_FLOATS];
    const int blk = blockIdx.x;            // b*16 + c
    const int b = blk >> 4, c = blk & 15;
    const int tid = threadIdx.x;
    if (blk == 0 && tid < NPS)
        wtab[tid] = 0.5f - 0.5f * __cosf((float)tid * TWOPI_128);
    welch_spectra<false>(tgt + (size_t)blk * LQ, nullptr, smem);
    const float2* s_y = (const float2*)(smem + OFF_Y);
    for (int i = tid; i < SQ * FQ; i += 256) {
        const int s2 = i / 65, k = i - 65 * s2;
        const float2 v = s_y[s2 * YLD + k];
        if (k < 64) {
            const int q = k >> 2, j = k & 3;
            xquad[((((size_t)b * 16 + q) * SQ + s2) * CQ + c) * 4 + j] = v;
        } else {
            xtail[((size_t)b * SQ + s2) * CQ + c] = v;
        }
    }
    if (tid < FQ) {
        float a = 0.f;
        for (int s = 0; s < SQ; ++s) {
            const float2 y = s_y[s * YLD + tid];
            a += y.x * y.x + y.y * y.y;
        }
        pxx[(size_t)blk * FQ + tid] = a * (1.0f / (float)SQ);
    }
}

// exact pk sequence of the proven kernel, as a macro so the pipeline can reuse it
#define SCORE_COMPUTE(XA, XB, YA, YB)                                            \
    do {                                                                         \
        const float2 x0 = make_float2((XA).x, (XA).y), x1 = make_float2((XA).z, (XA).w); \
        const float2 x2 = make_float2((XB).x, (XB).y), x3 = make_float2((XB).z, (XB).w); \
        const float2 y0 = make_float2((YA).x, (YA).y), y1 = make_float2((YA).z, (YA).w); \
        const float2 y2 = make_float2((YB).x, (YB).y), y3 = make_float2((YB).z, (YB).w); \
        a0 = pk_cma1(x0, y0, a0);  a0 = pk_cma2(x0, y0, a0);                     \
        a1 = pk_cma1(x1, y1, a1);  a1 = pk_cma2(x1, y1, a1);                     \
        a2 = pk_cma1(x2, y2, a2);  a2 = pk_cma2(x2, y2, a2);                     \
        a3 = pk_cma1(x3, y3, a3);  a3 = pk_cma2(x3, y3, a3);                     \
    } while (0)

// Score: one block per (b,n). Y spectra, Pyy, coherence vs 16 channels (packed fp32).
// Score loop is software-pipelined (depth 1): loads for s+1 issue before compute
// of s. (Depth-2, asymmetric, and full-unroll variants all collapsed in r5-r7 —
// depth-1 @ VGPR 40 is the stable optimum of this axis.) The g==0 bin-64 tail
// now prefetches its global xtail load at depth 1 too (same accumulation order).
__global__ __launch_bounds__(256) void k_score(const float* __restrict__ db,
                                               const float2* __restrict__ xquad,
                                               const float2* __restrict__ xtail,
                                               const float* __restrict__ pxx,
                                               const float* __restrict__ wtab,
                                               float* __restrict__ scores) {
    __shared__ float smem[SMEM_FLOATS];
    const int blk = blockIdx.x;            // b*2048 + n
    const int b = blk >> 11, n = blk & 2047;
    welch_spectra<true>(db + (size_t)blk * LQ, wtab, smem);
    float* s_pyy = smem + OFF_PYY;
    float* s_red = smem + OFF_RED;
    const int tid = threadIdx.x;

    if (tid < FQ) {
        float a = 0.f;
        for (int s = 0; s < SQ; ++s) {
            const float2 y = ((const float2*)(smem + OFF_Y))[s * YLD + tid];
            a += y.x * y.x + y.y * y.y;
        }
        s_pyy[tid] = a * (1.0f / (float)SQ);
    }
    __syncthreads();

    const int c = tid & 15, g = tid >> 4;
    const int f0 = 4 * g;
    // x quad pointer for (b, q=g, c): 2 float4 per (s,c); stride per s = 32 float4
    const float4* xp = (const float4*)xquad + (((size_t)(b * 16 + g) * SQ) * CQ + c) * 2;
    const float*  px = pxx + ((size_t)b * CQ + c) * FQ;
    const float*  ybase = smem + OFF_Y;
#define YADDR(S) ((const float4*)(ybase + (size_t)((S) * YLD + f0) * 2))

    float2 a0 = make_float2(0.f, 0.f), a1 = a0, a2 = a0, a3 = a0;   // {pr,pi}

    // prologue: s = 0 in flight
    float4 xa = xp[0], xb4 = xp[1];
    xp += 32;
    float4 ya = YADDR(0)[0], yb = YADDR(0)[1];

#pragma unroll 2
    for (int s = 0; s < SQ - 1; ++s) {      // s = 0..29; prefetch s+1 before compute
        const float4 xa_n = xp[0], xb_n = xp[1];
        xp += 32;
        const float4 ya_n = YADDR(s + 1)[0], yb_n = YADDR(s + 1)[1];
        SCORE_COMPUTE(xa, xb4, ya, yb);
        xa = xa_n; xb4 = xb_n; ya = ya_n; yb = yb_n;
    }
    SCORE_COMPUTE(xa, xb4, ya, yb);         // s = 30
#undef YADDR

    const float invS2 = 1.0f / ((float)SQ * (float)SQ);
    float acc = 0.f;
    acc += ((a0.x * a0.x + a0.y * a0.y) * invS2) / (px[f0 + 0] * s_pyy[f0 + 0] + EPSQ);
    acc += ((a1.x * a1.x + a1.y * a1.y) * invS2) / (px[f0 + 1] * s_pyy[f0 + 1] + EPSQ);
    acc += ((a2.x * a2.x + a2.y * a2.y) * invS2) / (px[f0 + 2] * s_pyy[f0 + 2] + EPSQ);
    acc += ((a3.x * a3.x + a3.y * a3.y) * invS2) / (px[f0 + 3] * s_pyy[f0 + 3] + EPSQ);

    if (g == 0) {                            // bin 64 tail, 16 threads, depth-1 prefetch
        float2 a4 = make_float2(0.f, 0.f);
        const float2* xt = xtail + (size_t)b * SQ * CQ + c;
        float2 x4 = xt[0];
        for (int s = 0; s < SQ - 1; ++s) {
            const float2 x4n = xt[(s + 1) * CQ];
            const float2 y4 = ((const float2*)(smem + OFF_Y))[s * YLD + 64];
            a4 = pk_cma1(x4, y4, a4);  a4 = pk_cma2(x4, y4, a4);
            x4 = x4n;
        }
        {
            const float2 y4 = ((const float2*)(smem + OFF_Y))[(SQ - 1) * YLD + 64];
            a4 = pk_cma1(x4, y4, a4);  a4 = pk_cma2(x4, y4, a4);
        }
        acc += ((a4.x * a4.x + a4.y * a4.y) * invS2) / (px[64] * s_pyy[64] + EPSQ);
    }

    s_red[tid] = acc;                       // tid = g*16 + c
    __syncthreads();
    if (tid < 16) {
        float a = 0.f;
#pragma unroll
        for (int gg = 0; gg < 16; ++gg) a += s_red[gg * 16 + tid];
        scores[((size_t)b * CQ + tid) * NQ + n] = a * (1.0f / (float)FQ);
    }
}

// Fused top-32 + gather: one block per (b,c) row. Selection loop is byte-identical
// to the proven k_topk (desc, ties->lowest idx; register-resident scores); the 32
// winning indices are kept in smem and the 32 output rows (8KB each) are copied
// in a bulk phase afterward. Output addresses/values identical to the split version.
__global__ __launch_bounds__(256) void k_topk_gather(const float* __restrict__ scores,
                                                     const float* __restrict__ db,
                                                     float* __restrict__ out) {
    __shared__ float rv[4];
    __shared__ int   ri[4];
    __shared__ int   sbj;
    __shared__ int   sidx[KQ];
    const int blk = blockIdx.x, tid = threadIdx.x;   // blk = b*16 + c
    const int b = blk >> 4;
    const float* row = scores + (size_t)blk * NQ;
    float v[8];
#pragma unroll
    for (int j = 0; j < 8; ++j) v[j] = row[tid + 256 * j];
    for (int k = 0; k < KQ; ++k) {
        float best = -3.402823466e38f;
        int bi = 0x7fffffff;
#pragma unroll
        for (int j = 0; j < 8; ++j) {
            if (v[j] > best) { best = v[j]; bi = tid + 256 * j; }  // ascending idx: strict > keeps smallest
        }
#pragma unroll
        for (int off = 1; off < 64; off <<= 1) {
            const float ov = __shfl_xor(best, off, 64);
            const int   oi = __shfl_xor(bi, off, 64);
            if (ov > best || (ov == best && oi < bi)) { best = ov; bi = oi; }
        }
        if ((tid & 63) == 0) { rv[tid >> 6] = best; ri[tid >> 6] = bi; }
        __syncthreads();
        if (tid == 0) {
            float bv = rv[0]; int bj = ri[0];
#pragma unroll
            for (int w2 = 1; w2 < 4; ++w2) {
                if (rv[w2] > bv || (rv[w2] == bv && ri[w2] < bj)) { bv = rv[w2]; bj = ri[w2]; }
            }
            sidx[k] = bj;
            sbj = bj;
        }
        __syncthreads();
        const int bj = sbj;
#pragma unroll
        for (int j = 0; j < 8; ++j)
            if (bj == tid + 256 * j) v[j] = -3.402823466e38f;
    }
    // bulk gather: 32 rows x 2048 floats -> out rows blk*32 .. blk*32+31
    float4* dstbase = (float4*)(out + (size_t)blk * KQ * LQ);
#pragma unroll 4
    for (int r = 0; r < KQ; ++r) {
        const int idx = sidx[r];
        const float4* src = (const float4*)(db + ((size_t)(b * NQ + idx)) * LQ);
        float4* dst = dstbase + (size_t)r * (LQ / 4);
        dst[tid] = src[tid];
        dst[tid + 256] = src[tid + 256];
    }
}

extern "C" void kernel_launch(void* const* d_in, const int* in_sizes, int n_in,
                              void* d_out, int out_size, void* d_ws, size_t ws_size,
                              hipStream_t stream) {
    const float* tgt = (const float*)d_in[0];   // [8,16,2048]
    const float* db  = (const float*)d_in[1];   // [8,2048,2048]
    float* out = (float*)d_out;                 // [8,512,2048]
    char* ws = (char*)d_ws;

    float2* xquad  = (float2*)(ws + XQ_OFF);
    float2* xtail  = (float2*)(ws + XTAIL_OFF);
    float*  pxx    = (float*)(ws + PXX_OFF);
    float*  scores = (float*)(ws + SCORES_OFF);
    float*  wtab   = (float*)(ws + WTAB_OFF);

    hipLaunchKernelGGL(k_xspec,       dim3(BQ * CQ), dim3(256), 0, stream, tgt, xquad, xtail, pxx, wtab);
    hipLaunchKernelGGL(k_score,       dim3(BQ * NQ), dim3(256), 0, stream, db, xquad, xtail, pxx, wtab, scores);
    hipLaunchKernelGGL(k_topk_gather, dim3(BQ * CQ), dim3(256), 0, stream, scores, db, out);
}